// Round 9
// baseline (109.840 us; speedup 1.0000x reference)
//
#include <hip/hip_runtime.h>

// ChamferLoss: B=4, C=3, N=M=8192 fp32.
// loss = 2 * mean_b( sum_n min_m ||q_n - r_m||^2 ), clamp >= 0.
// s(n,m) = q.r - 0.5*r^2 via v_mfma_f32_32x32x16_bf16, fp32 split as bf16
// hi+lo across K. Verified exact (absmax 0.0) in rounds 7-8.
//
// ROUND 9 = INSTRUMENTATION: K1 launched 3x (idempotent; out re-zeroed by
// block0 each launch, partial rewritten identically). dur - 74.8 ~= 2*K1
// gives K1's true per-instance marginal cost, deciding whether ~25us of
// attackable kernel time exists or we are at the harness floor.

#define NPTS  8192
#define NB    4
#define NCH   256      // 32-point q-chunks per batch
#define RR    8        // ref ranges (1024 refs each)
#define RCPR  32       // ref chunks per range
#define WPB   8        // waves per block = q-chunks per block
#define BT    (WPB*64) // 512 threads

typedef float f32x16 __attribute__((ext_vector_type(16)));
typedef short bf16x8 __attribute__((ext_vector_type(8)));

static __device__ __forceinline__ unsigned int f2bf(float f) {
    unsigned int u = __float_as_uint(f);
    u += 0x7FFF + ((u >> 16) & 1);          // RNE
    return u >> 16;
}
static __device__ __forceinline__ float bf2f(unsigned int s) {
    return __uint_as_float(s << 16);
}

// ---- Phase 1: convert + MFMA tiles + per-query running max ----
__global__ __launch_bounds__(BT) void chamfer_mfma(
    const float* __restrict__ pc2,       // queries [B,3,N]  (B operand)
    const float* __restrict__ pc1w,      // refs    [B,3,N]  (A operand)
    float* __restrict__ partial,         // [B, RR, NPTS] smax partials
    float* __restrict__ out)             // zeroed here for K2's atomics
{
    __shared__ uint4 slds[RCPR * 64];    // 32 KB: A-fragments for 1024 refs
    const int tid  = threadIdx.x;
    const int b    = blockIdx.z;
    const int rr   = blockIdx.y;
    const int wave = tid >> 6;
    const int lane = tid & 63;

    if (blockIdx.x == 0 && rr == 0 && b == 0 && tid == 0)
        out[0] = 0.0f;   // K2 accumulates; stream order makes this safe

    // stage + convert this range's 1024 refs into A-fragment layout
    const float* refb = pc1w + b * 3 * NPTS + rr * (RCPR * 32);
#pragma unroll
    for (int j = 0; j < 2; ++j) {
        int i = tid + j * BT;            // 0..1023, coalesced
        float x = refb[i], y = refb[NPTS + i], z = refb[2 * NPTS + i];
        unsigned xh = f2bf(x), yh = f2bf(y), zh = f2bf(z);
        unsigned xl = f2bf(x - bf2f(xh));
        unsigned yl = f2bf(y - bf2f(yh));
        unsigned zl = f2bf(z - bf2f(zh));
        float h = -0.5f * (x * x + y * y + z * z);
        unsigned hh = f2bf(h);
        unsigned hl = f2bf(h - bf2f(hh));
        int c = i >> 5, l32 = i & 31;
        // k0..7 = [xh,xl,xh,yh,yl,yh,zh,zl], k8..15 = [zh,hh,hl,0,...]
        slds[c * 64 + l32] =
            make_uint4(xh | (xl << 16), xh | (yh << 16),
                       yl | (yh << 16), zh | (zl << 16));
        slds[c * 64 + 32 + l32] = make_uint4(zh | (hh << 16), hl, 0u, 0u);
    }

    // per-lane query B-fragment (column = lane&31)
    const int qc = blockIdx.x * WPB + wave;
    const int qn = qc * 32 + (lane & 31);
    const float* qb = pc2 + b * 3 * NPTS;
    float x = qb[qn], y = qb[NPTS + qn], z = qb[2 * NPTS + qn];
    unsigned xh = f2bf(x), yh = f2bf(y), zh = f2bf(z);
    unsigned xl = f2bf(x - bf2f(xh));
    unsigned yl = f2bf(y - bf2f(yh));
    unsigned zl = f2bf(z - bf2f(zh));
    // k0..7 = [xh,xh,xl,yh,yh,yl,zh,zh], k8..15 = [zl,1,1,0,...]
    uint4 bu = (lane < 32)
        ? make_uint4(xh | (xh << 16), xl | (yh << 16),
                     yh | (yl << 16), zh | (zh << 16))
        : make_uint4(zl | (0x3F80u << 16), 0x3F80u, 0u, 0u);
    bf16x8 bq = __builtin_bit_cast(bf16x8, bu);

    __syncthreads();

    f32x16 zero;
#pragma unroll
    for (int i = 0; i < 16; ++i) zero[i] = 0.0f;

    float rm0 = -3e38f, rm1 = -3e38f, rm2 = -3e38f, rm3 = -3e38f;
    const int abase = (lane >> 5) * 32 + (lane & 31);
#pragma unroll 2
    for (int c = 0; c < RCPR; ++c) {
        bf16x8 a = __builtin_bit_cast(bf16x8, slds[c * 64 + abase]);
        f32x16 d = __builtin_amdgcn_mfma_f32_32x32x16_bf16(a, bq, zero, 0, 0, 0);
        rm0 = fmaxf(rm0, fmaxf(d[0],  d[1]));   // rows = refs
        rm0 = fmaxf(rm0, fmaxf(d[2],  d[3]));
        rm1 = fmaxf(rm1, fmaxf(d[4],  d[5]));
        rm1 = fmaxf(rm1, fmaxf(d[6],  d[7]));
        rm2 = fmaxf(rm2, fmaxf(d[8],  d[9]));
        rm2 = fmaxf(rm2, fmaxf(d[10], d[11]));
        rm3 = fmaxf(rm3, fmaxf(d[12], d[13]));
        rm3 = fmaxf(rm3, fmaxf(d[14], d[15]));
    }
    float rm = fmaxf(fmaxf(rm0, rm1), fmaxf(rm2, rm3));
    // lanes l and l^32 hold the two row-halves of the same query column
    rm = fmaxf(rm, __shfl_xor(rm, 32, 64));
    if (lane < 32)
        partial[(b * RR + rr) * NPTS + qc * 32 + lane] = rm;
}

// ---- Phase 2: finalize ----
__global__ __launch_bounds__(512) void chamfer_reduce(
    const float* __restrict__ pc2,
    const float* __restrict__ partial,
    float* __restrict__ out)
{
    const int g = blockIdx.x * 512 + threadIdx.x;   // query id
    const int b = g >> 13, n = g & 8191;
    float smax = -3e38f;
#pragma unroll
    for (int c = 0; c < RR; ++c)
        smax = fmaxf(smax, partial[(b * RR + c) * NPTS + n]);

    const float* qb = pc2 + b * 3 * NPTS;
    float qx = qb[n], qy = qb[NPTS + n], qz = qb[2 * NPTS + n];
    float q2 = qx * qx + qy * qy + qz * qz;
    float d = fmaxf(q2 - 2.0f * smax, 0.0f);

#pragma unroll
    for (int off = 32; off > 0; off >>= 1)
        d += __shfl_down(d, off, 64);

    __shared__ float wsum[8];
    const int lane = threadIdx.x & 63;
    const int wid  = threadIdx.x >> 6;
    if (lane == 0) wsum[wid] = d;
    __syncthreads();
    if (threadIdx.x == 0) {
        float s = 0.0f;
#pragma unroll
        for (int w = 0; w < 8; ++w) s += wsum[w];
        atomicAdd(out, s * (2.0f / NB));   // 2 * mean over batches
    }
}

extern "C" void kernel_launch(void* const* d_in, const int* in_sizes, int n_in,
                              void* d_out, int out_size, void* d_ws, size_t ws_size,
                              hipStream_t stream) {
    const float* pc2  = (const float*)d_in[0];
    const float* pc1w = (const float*)d_in[1];
    float* out = (float*)d_out;
    float* partial = (float*)d_ws;   // B * RR * NPTS * 4 = 1 MiB

    dim3 g1(NCH / WPB, RR, NB);      // (32, 8, 4) = 1024 blocks
    // Launched 3x ON PURPOSE (idempotent): dur delta vs round-8's single
    // launch measures K1's true marginal cost (rocprof top-5 is all fills).
    chamfer_mfma<<<g1, BT, 0, stream>>>(pc2, pc1w, partial, out);
    chamfer_mfma<<<g1, BT, 0, stream>>>(pc2, pc1w, partial, out);
    chamfer_mfma<<<g1, BT, 0, stream>>>(pc2, pc1w, partial, out);
    chamfer_reduce<<<NB * NPTS / 512, 512, 0, stream>>>(pc2, partial, out);
}

// Round 10
// 73.521 us; speedup vs baseline: 1.4940x; 1.4940x over previous
//
#include <hip/hip_runtime.h>

// ChamferLoss: B=4, C=3, N=M=8192 fp32.
// loss = 2 * mean_b( sum_n min_m ||q_n - r_m||^2 ), clamp >= 0.
// s(n,m) = q.r - 0.5*r^2 via v_mfma_f32_32x32x16_bf16, fp32 split as bf16
// hi+lo across K. Verified exact (absmax 0.0) in rounds 7-9.
//
// ROUND 10: A-operand reuse — each wave holds 2 query B-fragments and does
// 2 MFMAs per ds_read_b128 (MFMA:LDS cycle ratio 16:12 instead of 8:12);
// grid (16,8,4)=512 blocks = 2 blocks/CU = ONE dispatch round; explicit
// next-chunk prefetch breaks the ds_read->MFMA dependence chain.
// (R9 instrumentation: K1 marginal cost 17.5us vs ~4-5us pipe model.)

#define NPTS  8192
#define NB    4
#define NCH   256      // 32-point q-chunks per batch
#define RR    8        // ref ranges (1024 refs each)
#define RCPR  32       // ref chunks per range
#define WPB   8        // waves per block
#define BT    (WPB*64) // 512 threads
#define QPW   2        // q-chunks per wave

typedef float f32x16 __attribute__((ext_vector_type(16)));
typedef short bf16x8 __attribute__((ext_vector_type(8)));

static __device__ __forceinline__ unsigned int f2bf(float f) {
    unsigned int u = __float_as_uint(f);
    u += 0x7FFF + ((u >> 16) & 1);          // RNE
    return u >> 16;
}
static __device__ __forceinline__ float bf2f(unsigned int s) {
    return __uint_as_float(s << 16);
}

// ---- Phase 1: convert + MFMA tiles + per-query running max ----
__global__ __launch_bounds__(BT, 4) void chamfer_mfma(
    const float* __restrict__ pc2,       // queries [B,3,N]  (B operand)
    const float* __restrict__ pc1w,      // refs    [B,3,N]  (A operand)
    float* __restrict__ partial,         // [B, RR, NPTS] smax partials
    float* __restrict__ out)             // zeroed here for K2's atomics
{
    __shared__ uint4 slds[RCPR * 64];    // 32 KB: A-fragments for 1024 refs
    const int tid  = threadIdx.x;
    const int b    = blockIdx.z;
    const int rr   = blockIdx.y;
    const int wave = tid >> 6;
    const int lane = tid & 63;

    if (blockIdx.x == 0 && rr == 0 && b == 0 && tid == 0)
        out[0] = 0.0f;   // K2 accumulates; stream order makes this safe

    // stage + convert this range's 1024 refs into A-fragment layout
    const float* refb = pc1w + b * 3 * NPTS + rr * (RCPR * 32);
#pragma unroll
    for (int j = 0; j < 2; ++j) {
        int i = tid + j * BT;            // 0..1023, coalesced
        float x = refb[i], y = refb[NPTS + i], z = refb[2 * NPTS + i];
        unsigned xh = f2bf(x), yh = f2bf(y), zh = f2bf(z);
        unsigned xl = f2bf(x - bf2f(xh));
        unsigned yl = f2bf(y - bf2f(yh));
        unsigned zl = f2bf(z - bf2f(zh));
        float h = -0.5f * (x * x + y * y + z * z);
        unsigned hh = f2bf(h);
        unsigned hl = f2bf(h - bf2f(hh));
        int c = i >> 5, l32 = i & 31;
        // lanes 0..31 read g0 (k0..7), lanes 32..63 read g1 (k8..15):
        // A k0..7 = [xh,xl,xh,yh,yl,yh,zh,zl], k8..15 = [zh,hh,hl,0,...]
        slds[c * 64 + l32] =
            make_uint4(xh | (xl << 16), xh | (yh << 16),
                       yl | (yh << 16), zh | (zl << 16));
        slds[c * 64 + 32 + l32] = make_uint4(zh | (hh << 16), hl, 0u, 0u);
    }

    // two per-lane query B-fragments (columns = lane&31 of q-chunks qc0,qc0+1)
    const int qc0 = (blockIdx.x * WPB + wave) * QPW;
    const float* qb = pc2 + b * 3 * NPTS;
    bf16x8 bq[QPW];
#pragma unroll
    for (int j = 0; j < QPW; ++j) {
        int qn = (qc0 + j) * 32 + (lane & 31);
        float x = qb[qn], y = qb[NPTS + qn], z = qb[2 * NPTS + qn];
        unsigned xh = f2bf(x), yh = f2bf(y), zh = f2bf(z);
        unsigned xl = f2bf(x - bf2f(xh));
        unsigned yl = f2bf(y - bf2f(yh));
        unsigned zl = f2bf(z - bf2f(zh));
        // B k0..7 = [xh,xh,xl,yh,yh,yl,zh,zh], k8..15 = [zl,1,1,0,...]
        uint4 bu = (lane < 32)
            ? make_uint4(xh | (xh << 16), xl | (yh << 16),
                         yh | (yl << 16), zh | (zh << 16))
            : make_uint4(zl | (0x3F80u << 16), 0x3F80u, 0u, 0u);
        bq[j] = __builtin_bit_cast(bf16x8, bu);
    }

    __syncthreads();

    f32x16 zero;
#pragma unroll
    for (int i = 0; i < 16; ++i) zero[i] = 0.0f;

    float rma0 = -3e38f, rma1 = -3e38f, rma2 = -3e38f, rma3 = -3e38f;
    float rmb0 = -3e38f, rmb1 = -3e38f, rmb2 = -3e38f, rmb3 = -3e38f;

    bf16x8 a = __builtin_bit_cast(bf16x8, slds[lane]);   // chunk 0 prefetched
#pragma unroll 4
    for (int c = 0; c < RCPR; ++c) {
        bf16x8 acur = a;
        if (c + 1 < RCPR)
            a = __builtin_bit_cast(bf16x8, slds[(c + 1) * 64 + lane]);
        f32x16 d0 = __builtin_amdgcn_mfma_f32_32x32x16_bf16(acur, bq[0], zero, 0, 0, 0);
        f32x16 d1 = __builtin_amdgcn_mfma_f32_32x32x16_bf16(acur, bq[1], zero, 0, 0, 0);
        rma0 = fmaxf(rma0, fmaxf(d0[0],  d0[1]));   // rows = refs
        rma0 = fmaxf(rma0, fmaxf(d0[2],  d0[3]));
        rma1 = fmaxf(rma1, fmaxf(d0[4],  d0[5]));
        rma1 = fmaxf(rma1, fmaxf(d0[6],  d0[7]));
        rma2 = fmaxf(rma2, fmaxf(d0[8],  d0[9]));
        rma2 = fmaxf(rma2, fmaxf(d0[10], d0[11]));
        rma3 = fmaxf(rma3, fmaxf(d0[12], d0[13]));
        rma3 = fmaxf(rma3, fmaxf(d0[14], d0[15]));
        rmb0 = fmaxf(rmb0, fmaxf(d1[0],  d1[1]));
        rmb0 = fmaxf(rmb0, fmaxf(d1[2],  d1[3]));
        rmb1 = fmaxf(rmb1, fmaxf(d1[4],  d1[5]));
        rmb1 = fmaxf(rmb1, fmaxf(d1[6],  d1[7]));
        rmb2 = fmaxf(rmb2, fmaxf(d1[8],  d1[9]));
        rmb2 = fmaxf(rmb2, fmaxf(d1[10], d1[11]));
        rmb3 = fmaxf(rmb3, fmaxf(d1[12], d1[13]));
        rmb3 = fmaxf(rmb3, fmaxf(d1[14], d1[15]));
    }
    float rma = fmaxf(fmaxf(rma0, rma1), fmaxf(rma2, rma3));
    float rmb = fmaxf(fmaxf(rmb0, rmb1), fmaxf(rmb2, rmb3));
    // lanes l and l^32 hold the two row-halves of the same query column
    rma = fmaxf(rma, __shfl_xor(rma, 32, 64));
    rmb = fmaxf(rmb, __shfl_xor(rmb, 32, 64));
    float* pb = partial + (b * RR + rr) * NPTS + qc0 * 32;
    if (lane < 32) {
        pb[lane]      = rma;
        pb[32 + lane] = rmb;
    }
}

// ---- Phase 2: finalize ----
__global__ __launch_bounds__(512) void chamfer_reduce(
    const float* __restrict__ pc2,
    const float* __restrict__ partial,
    float* __restrict__ out)
{
    const int g = blockIdx.x * 512 + threadIdx.x;   // query id
    const int b = g >> 13, n = g & 8191;
    float smax = -3e38f;
#pragma unroll
    for (int c = 0; c < RR; ++c)
        smax = fmaxf(smax, partial[(b * RR + c) * NPTS + n]);

    const float* qb = pc2 + b * 3 * NPTS;
    float qx = qb[n], qy = qb[NPTS + n], qz = qb[2 * NPTS + n];
    float q2 = qx * qx + qy * qy + qz * qz;
    float d = fmaxf(q2 - 2.0f * smax, 0.0f);

#pragma unroll
    for (int off = 32; off > 0; off >>= 1)
        d += __shfl_down(d, off, 64);

    __shared__ float wsum[8];
    const int lane = threadIdx.x & 63;
    const int wid  = threadIdx.x >> 6;
    if (lane == 0) wsum[wid] = d;
    __syncthreads();
    if (threadIdx.x == 0) {
        float s = 0.0f;
#pragma unroll
        for (int w = 0; w < 8; ++w) s += wsum[w];
        atomicAdd(out, s * (2.0f / NB));   // 2 * mean over batches
    }
}

extern "C" void kernel_launch(void* const* d_in, const int* in_sizes, int n_in,
                              void* d_out, int out_size, void* d_ws, size_t ws_size,
                              hipStream_t stream) {
    const float* pc2  = (const float*)d_in[0];
    const float* pc1w = (const float*)d_in[1];
    float* out = (float*)d_out;
    float* partial = (float*)d_ws;   // B * RR * NPTS * 4 = 1 MiB

    dim3 g1(NCH / (WPB * QPW), RR, NB);   // (16, 8, 4) = 512 blocks
    chamfer_mfma<<<g1, BT, 0, stream>>>(pc2, pc1w, partial, out);
    chamfer_reduce<<<NB * NPTS / 512, 512, 0, stream>>>(pc2, partial, out);
}